// Round 11
// baseline (22584.772 us; speedup 1.0000x reference)
//
#include <hip/hip_runtime.h>
#include <math.h>

#define V 13000
#define D 300
#define M 500
#define B 64
#define NW 5
#define T 128
#define NSUP (B*NW)        // 320
#define NSEQ (NSUP + B)    // 384
#define NCT64 6            // chain tiles of 64
#define NMT 126            // m tiles of 4 (504 slots, clamp at 500)
#define KROW 800           // act row: k<300 = x, k>=300 = c(m=k-300)
#define NSTEP (T-1)        // 127
#define NCOMPX (2*NCT64*NMT)   // 1512 compute blocks (1 wave each)
#define NGATH 48               // 2 dir * 6 rank-tiles * 4 k-phases
#define TCHK 20            // ticks per A chunk
#define NCK 5              // chunks (5*20 = 100 ticks per ksub stripe)
#define ASTRIPE 340        // floats per stripe: 5 kq * 68 (64 + 4 skew)
#define SMEMF (8*ASTRIPE)  // 2720 floats = 10.9 KB per wave

__device__ __forceinline__ float sigmoidf_(float x){ return 1.0f/(1.0f+expf(-x)); }

// actB layout: actB[(d*KROW + k)*NSEQ + rank]
// c_final layout: c_final[(d*NSEQ + chain)*M + m]
// A LDS (per wave): float off = stripe*340 + kq*68 + j*16 + row;  tick t=(kq*4+j),
//   row = g*4+mj.  Read t: F(t) = t*16 + (t>>2)*4, rows 0..11 as 3 float4.

__global__ void init_kernel(const float* __restrict__ c0L, const float* __restrict__ c0R,
                            float* __restrict__ actB0, float* __restrict__ c_final)
{
    int idx = blockIdx.x*256 + threadIdx.x;      // 2*M*NSEQ
    if (idx >= 2*M*NSEQ) return;
    int d = idx / (M*NSEQ);
    int rem = idx % (M*NSEQ);
    int m = rem / NSEQ;
    int r = rem % NSEQ;
    float v = d ? c0R[m] : c0L[m];
    actB0[((size_t)d*KROW + 300 + m)*NSEQ + r] = v;
    c_final[((size_t)d*NSEQ + r)*M + m] = v;
}

__global__ void sort_kernel(const int* __restrict__ blank_sup, const int* __restrict__ blank_tgt,
                            int* __restrict__ perm, int* __restrict__ lenR, int* __restrict__ tmax)
{
    __shared__ int L0[NSEQ], L1[NSEQ];
    int tid = threadIdx.x;                       // 384 threads
    int blank = (tid < NSUP) ? blank_sup[tid] : blank_tgt[tid - NSUP];
    int l0 = blank, l1 = (T-1) - blank;
    L0[tid] = l0; L1[tid] = l1;
    __syncthreads();
    int r0 = 0, r1 = 0;
    for (int j = 0; j < NSEQ; ++j) {
        int c = L0[j]; r0 += (c > l0) || (c == l0 && j < tid);
        int d = L1[j]; r1 += (d > l1) || (d == l1 && j < tid);
    }
    perm[r0] = tid;        lenR[r0] = l0;
    perm[NSEQ + r1] = tid; lenR[NSEQ + r1] = l1;
    __syncthreads();
    if (tid < 2*NCT64) {
        int dir = tid / NCT64, t = tid % NCT64;
        tmax[tid] = lenR[dir*NSEQ + t*64];       // descending -> first rank of 64-tile is max
    }
}

// -------- per-step kernel: 1512 one-wave compute blocks + 48 gather blocks --------
// compute wave = (d, ct: 64 chains, mt: 4 m) x 3 gates; lane = ksub*8 + cg;
// lane tile = 4m x 3g x 8c over K=100 (its ksub stripe). No barriers at all.
__global__ __launch_bounds__(64, 2)
void step_kernel(int s,
                 const float* __restrict__ actB_cur, float* __restrict__ actB_next,
                 float* __restrict__ c_final,
                 const float* __restrict__ WL, const float* __restrict__ UL, const float* __restrict__ bL,
                 const float* __restrict__ WR, const float* __restrict__ UR, const float* __restrict__ bR,
                 const int* __restrict__ perm, const int* __restrict__ lenR, const int* __restrict__ tmax,
                 const int* __restrict__ sup_tok, const int* __restrict__ tgt_tok,
                 const float* __restrict__ emb)
{
    const int bid = blockIdx.x;
    const int lane = threadIdx.x;                // 0..63

    if (bid >= NCOMPX) {
        // ---- gather x for step s+1 (coalesced: lane = rank) ----
        const int gb = bid - NCOMPX;             // 0..47
        const int d  = gb / 24;
        const int rem = gb % 24;
        const int rt = rem >> 2;                 // 64-rank tile
        const int kk = rem & 3;                  // k phase
        const int sn = s + 1;
        if (sn >= NSTEP) return;
        if (sn >= tmax[d*NCT64 + rt]) return;
        const int rank = rt*64 + lane;
        const int ch = perm[d*NSEQ + rank];
        const int tpos = d ? (T-1 - sn) : sn;
        const int tok = (ch < NSUP) ? sup_tok[ch*T + tpos] : tgt_tok[(ch-NSUP)*T + tpos];
        const float* src = emb + (size_t)tok*D + kk;
        float* dst = actB_next + ((size_t)d*KROW + kk)*NSEQ + rank;
        #pragma unroll 5
        for (int k4 = 0; k4 < 75; ++k4)
            dst[(size_t)(k4*4)*NSEQ] = src[k4*4];
        return;
    }
    if (s < 0) return;

    // bid = (d*6+ct)*126 + mt  -> blocks of one act-tile dispatch-adjacent (L2 locality)
    const int mt  = bid % NMT;
    const int dct = bid / NMT;                   // 0..11
    const int d   = dct / NCT64;
    const int ct  = dct % NCT64;
    if (s >= tmax[dct]) return;
    const int m0    = mt*4;
    const int rank0 = ct*64;

    __shared__ __align__(16) float smem[SMEMF];

    const int ksub = lane >> 3;                  // K stripe: k in [ksub*100, ksub*100+100)
    const int cg   = lane & 7;                   // chain octet: c = cg*8 .. cg*8+7

    const float* Wd = d ? WR : WL;
    const float* Ud = d ? UR : UL;
    const float* bias = d ? bR : bL;

    // ---- hoisted A staging geometry: 480 f4 slots = 8 stripes x 12 rows x 5 kq ----
    const float* aSrc[8]; int aOff[8]; bool aVal[8];
    #pragma unroll
    for (int i = 0; i < 8; ++i) {
        int slt = lane + 64*i;
        aVal[i] = (slt < 480);
        int s2 = aVal[i] ? slt : 0;
        int stripe = s2 / 60;
        int r = s2 % 60;
        int row = r / 5;                         // g*4 + mj
        int kq  = r % 5;
        int g = row >> 2, mj = row & 3;
        int m = m0 + mj; if (m >= M) m = M - 1;  // clamp (update discards)
        const float* base = (stripe < 3)
            ? (Wd + (size_t)(g*M + m)*D + stripe*100)
            : (Ud + (size_t)(g*M + m)*M + (stripe*100 - 300));
        aSrc[i] = base + kq*4;
        aOff[i] = stripe*ASTRIPE + kq*68 + row;
    }

    float4 as[8];
    auto ldA = [&](int ck){
        #pragma unroll
        for (int i = 0; i < 8; ++i)
            if (aVal[i]) as[i] = *(const float4*)(aSrc[i] + ck*TCHK);
    };
    auto wrA = [&](){
        #pragma unroll
        for (int i = 0; i < 8; ++i) if (aVal[i]) {
            float* p = smem + aOff[i];
            p[0] = as[i].x; p[16] = as[i].y; p[32] = as[i].z; p[48] = as[i].w;
        }
    };

    float acc[12][8];
    #pragma unroll
    for (int r = 0; r < 12; ++r)
        #pragma unroll
        for (int c = 0; c < 8; ++c) acc[r][c] = 0.f;

    const float* Ard = smem + ksub*ASTRIPE;
    const float* bp  = actB_cur + ((size_t)d*KROW + ksub*100)*NSEQ + rank0 + cg*8;

    // ---- K loop: 5 chunks x 20 ticks, A via LDS broadcast, B global->reg ----
    ldA(0);
    float4 bc0 = *(const float4*)bp;
    float4 bc1 = *(const float4*)(bp + 4);
    bp += NSEQ;

#define ROWFMA(r, av) \
    acc[r][0] += (av)*bc0.x; acc[r][1] += (av)*bc0.y; acc[r][2] += (av)*bc0.z; acc[r][3] += (av)*bc0.w; \
    acc[r][4] += (av)*bc1.x; acc[r][5] += (av)*bc1.y; acc[r][6] += (av)*bc1.z; acc[r][7] += (av)*bc1.w;

    for (int ck = 0; ck < NCK; ++ck) {
        wrA();                                   // stage chunk ck (in-order per-wave DS)
        if (ck + 1 < NCK) ldA(ck + 1);           // prefetch next chunk (hidden by compute)
        float4 aC0 = *(const float4*)(Ard + 0);
        float4 aC1 = *(const float4*)(Ard + 4);
        float4 aC2 = *(const float4*)(Ard + 8);
        #pragma unroll
        for (int t = 0; t < TCHK; ++t) {
            const int Fn = (t+1)*16 + ((t+1)>>2)*4;
            float4 aN0 = aC0, aN1 = aC1, aN2 = aC2;
            if (t < TCHK-1) {
                aN0 = *(const float4*)(Ard + Fn);
                aN1 = *(const float4*)(Ard + Fn + 4);
                aN2 = *(const float4*)(Ard + Fn + 8);
            }
            float4 bn0 = bc0, bn1 = bc1;
            if (!(ck == NCK-1 && t == TCHK-1)) {
                bn0 = *(const float4*)bp;
                bn1 = *(const float4*)(bp + 4);
                bp += NSEQ;
            }
            ROWFMA(0,  aC0.x) ROWFMA(1,  aC0.y) ROWFMA(2,  aC0.z) ROWFMA(3,  aC0.w)
            ROWFMA(4,  aC1.x) ROWFMA(5,  aC1.y) ROWFMA(6,  aC1.z) ROWFMA(7,  aC1.w)
            ROWFMA(8,  aC2.x) ROWFMA(9,  aC2.y) ROWFMA(10, aC2.z) ROWFMA(11, aC2.w)
            aC0 = aN0; aC1 = aN1; aC2 = aN2;
            bc0 = bn0; bc1 = bn1;
        }
    }
#undef ROWFMA

    // ---- reduce across ksub (lane bits 3,4,5) ----
    #pragma unroll
    for (int r = 0; r < 12; ++r)
        #pragma unroll
        for (int c = 0; c < 8; ++c) {
            float v = acc[r][c];
            v += __shfl_xor(v, 8);
            v += __shfl_xor(v, 16);
            v += __shfl_xor(v, 32);
            acc[r][c] = v;
        }

    // ---- cell update: all lanes compute (identical per cg); ksub==0 stores ----
    #pragma unroll
    for (int mj = 0; mj < 4; ++mj) {
        const int m = m0 + mj;
        if (m >= M) continue;                    // wave-uniform
        const float bf = bias[m], bi = bias[M + m], bc = bias[2*M + m];
        #pragma unroll
        for (int cc = 0; cc < 8; ++cc) {
            const int rank = rank0 + cg*8 + cc;
            const int len  = lenR[d*NSEQ + rank];
            const size_t cidx = ((size_t)d*KROW + 300 + m)*NSEQ + rank;
            float cold = actB_cur[cidx];
            float f  = sigmoidf_(acc[mj][cc]     + bf);
            float i2 = sigmoidf_(acc[4 + mj][cc] + bi);
            float cb = tanhf   (acc[8 + mj][cc]  + bc);
            float cn = (s < len) ? (f*cold + i2*cb) : cold;
            if (ksub == 0) {
                actB_next[cidx] = cn;
                if (s == len - 1) {
                    int ch = perm[d*NSEQ + rank];
                    c_final[((size_t)d*NSEQ + ch)*M + m] = cn;
                }
            }
        }
    }
}

__global__ void env_kernel(const float* __restrict__ l_states, const float* __restrict__ r_states,
                           const float* __restrict__ Wo, const float* __restrict__ Uo,
                           const float* __restrict__ bo,
                           float* __restrict__ env)
{
    __shared__ __align__(16) float l[M];
    __shared__ __align__(16) float r[M];
    const int i = blockIdx.x;
    const int tid = threadIdx.x;
    for (int m=tid; m<M; m+=blockDim.x){ l[m]=l_states[i*M+m]; r[m]=r_states[i*M+m]; }
    __syncthreads();
    for (int d=tid; d<D; d+=blockDim.x) {
        const float4* wo = reinterpret_cast<const float4*>(Wo + (size_t)d*M);
        const float4* uo = reinterpret_cast<const float4*>(Uo + (size_t)d*M);
        const float4* lv = reinterpret_cast<const float4*>(l);
        const float4* rv = reinterpret_cast<const float4*>(r);
        float acc = bo[d];
        #pragma unroll 5
        for (int q=0; q<M/4; ++q) {
            float4 a=wo[q], bv=lv[q], u=uo[q], rr=rv[q];
            acc += a.x*bv.x + a.y*bv.y + a.z*bv.z + a.w*bv.w;
            acc += u.x*rr.x + u.y*rr.y + u.z*rr.z + u.w*rr.w;
        }
        env[i*D + d] = tanhf(acc);
    }
}

__global__ void episode_kernel(const float* __restrict__ env, const int* __restrict__ target_y,
                               float* __restrict__ flags, float* __restrict__ losses)
{
    const int b = blockIdx.x;
    const int lane = threadIdx.x;
    const float* tgt = env + (size_t)(NSUP + b)*D;

    float tn = 0.f;
    for (int d=lane; d<D; d+=64){ float v=tgt[d]; tn += v*v; }
    for (int off=32; off; off>>=1) tn += __shfl_down(tn, off);
    tn = __shfl(tn, 0);

    float z[NW];
    for (int n=0; n<NW; ++n){
        const float* sup = env + (size_t)(b*NW + n)*D;
        float dot=0.f, sn=0.f;
        for (int d=lane; d<D; d+=64){ float sv=sup[d], tv=tgt[d]; dot+=sv*tv; sn+=sv*sv; }
        for (int off=32; off; off>>=1){ dot += __shfl_down(dot,off); sn += __shfl_down(sn,off); }
        dot = __shfl(dot,0); sn = __shfl(sn,0);
        float denom = fmaxf(sqrtf(sn)*sqrtf(tn), 1e-8f);
        z[n] = dot/denom*10.0f;
    }

    if (lane==0){
        float mx=z[0];
        for(int n=1;n<NW;n++) mx=fmaxf(mx,z[n]);
        float se=0.f; float p[NW];
        for(int n=0;n<NW;n++){ p[n]=expf(z[n]-mx); se+=p[n]; }
        for(int n=0;n<NW;n++) p[n]/=se;
        int am=0; float bv=p[0];
        for(int n=1;n<NW;n++) if(p[n]>bv){bv=p[n];am=n;}
        int y = target_y[b];
        flags[b] = (am==y)?1.0f:0.0f;
        float mx2=p[0]; for(int n=1;n<NW;n++) mx2=fmaxf(mx2,p[n]);
        float se2=0.f; for(int n=0;n<NW;n++) se2+=expf(p[n]-mx2);
        losses[b] = -(p[y]-mx2-logf(se2));
    }
}

__global__ void finalize_kernel(const float* __restrict__ flags, const float* __restrict__ losses,
                                float* __restrict__ out)
{
    const int lane = threadIdx.x; // 64 threads
    float f = flags[lane], l = losses[lane];
    for (int off=32; off; off>>=1){ f += __shfl_down(f,off); l += __shfl_down(l,off); }
    if (lane==0){ out[0] = f/(float)B; out[1] = l/(float)B; }
}

extern "C" void kernel_launch(void* const* d_in, const int* in_sizes, int n_in,
                              void* d_out, int out_size, void* d_ws, size_t ws_size,
                              hipStream_t stream) {
    const int*   sup_tok   = (const int*)d_in[0];
    const int*   tgt_tok   = (const int*)d_in[1];
    const int*   blank_sup = (const int*)d_in[2];
    const int*   blank_tgt = (const int*)d_in[3];
    const int*   target_y  = (const int*)d_in[4];
    const float* emb = (const float*)d_in[5];
    const float* WL  = (const float*)d_in[6];
    const float* UL  = (const float*)d_in[7];
    const float* bL  = (const float*)d_in[8];
    const float* WR  = (const float*)d_in[9];
    const float* UR  = (const float*)d_in[10];
    const float* bR  = (const float*)d_in[11];
    const float* Wo  = (const float*)d_in[12];
    const float* Uo  = (const float*)d_in[13];
    const float* bo  = (const float*)d_in[14];
    const float* c0L = (const float*)d_in[15];
    const float* c0R = (const float*)d_in[16];

    const size_t ACTSZ = (size_t)2*KROW*NSEQ;           // 614400 floats
    float* ws_f = (float*)d_ws;
    float* actB0   = ws_f;
    float* actB1   = actB0 + ACTSZ;
    float* c_final = actB1 + ACTSZ;                     // [2*384*500]
    float* env     = c_final + 2*NSEQ*M;                // [384*300]
    float* flags   = env + NSEQ*D;                      // [64]
    float* losses  = flags + B;                         // [64]
    int*   perm    = (int*)(losses + B);                // [2*384]
    int*   lenR    = perm + 2*NSEQ;                     // [2*384]
    int*   tmax    = lenR + 2*NSEQ;                     // [12]

    init_kernel<<<(2*M*NSEQ + 255)/256, 256, 0, stream>>>(c0L, c0R, actB0, c_final);
    sort_kernel<<<1, NSEQ, 0, stream>>>(blank_sup, blank_tgt, perm, lenR, tmax);

    // prologue: gather x for step 0 into actB0 (compute blocks no-op at s=-1)
    step_kernel<<<NCOMPX + NGATH, 64, 0, stream>>>(-1, actB1, actB0, c_final,
                                                   WL, UL, bL, WR, UR, bR,
                                                   perm, lenR, tmax, sup_tok, tgt_tok, emb);
    for (int s = 0; s < NSTEP; ++s) {
        float* cur  = (s & 1) ? actB1 : actB0;
        float* next = (s & 1) ? actB0 : actB1;
        step_kernel<<<NCOMPX + NGATH, 64, 0, stream>>>(s, cur, next, c_final,
                                                       WL, UL, bL, WR, UR, bR,
                                                       perm, lenR, tmax, sup_tok, tgt_tok, emb);
    }

    env_kernel<<<NSEQ, 256, 0, stream>>>(c_final, c_final + NSEQ*M, Wo, Uo, bo, env);
    episode_kernel<<<B, 64, 0, stream>>>(env, target_y, flags, losses);
    finalize_kernel<<<1, 64, 0, stream>>>(flags, losses, (float*)d_out);
}

// Round 12
// 6472.657 us; speedup vs baseline: 3.4893x; 3.4893x over previous
//
#include <hip/hip_runtime.h>
#include <math.h>

#define V 13000
#define D 300
#define M 500
#define B 64
#define NW 5
#define T 128
#define NSUP (B*NW)        // 320
#define NSEQ (NSUP + B)    // 384
#define CT 32              // chains per compute tile
#define NCT 12             // 384/32
#define MT 16              // m per block
#define KSPL 4             // K splits (one wave each)
#define CHK 20             // k per chunk
#define CKS 10             // chunks per split (4*10*20 = 800)
#define KROW 800           // act row: k<300 = x, k>=300 = c(m=k-300)
#define NSTEP (T-1)        // 127
#define ASTR 28            // LDS floats per A row (20 k + 8 pad, 16B aligned, 2-way banks)
#define APW (48*ASTR)      // 1344 floats per wave (48 rows x 28)
#define SMSZ 6144          // max(4*1344=5376, red 4*16*3*32=6144)
#define NCOMP 768          // 12 ct * 2 dir * 32 mt
#define NGATH 12           // 2 dir * 6 rank-tiles of 64

__device__ __forceinline__ float sigmoidf_(float x){ return 1.0f/(1.0f+expf(-x)); }

// actB layout: actB[(d*KROW + k)*NSEQ + rank]
// c_final layout: c_final[(d*NSEQ + chain)*M + m]

__global__ void init_kernel(const float* __restrict__ c0L, const float* __restrict__ c0R,
                            float* __restrict__ actB0, float* __restrict__ c_final)
{
    int idx = blockIdx.x*256 + threadIdx.x;      // 2*M*NSEQ
    if (idx >= 2*M*NSEQ) return;
    int d = idx / (M*NSEQ);
    int rem = idx % (M*NSEQ);
    int m = rem / NSEQ;
    int r = rem % NSEQ;
    float v = d ? c0R[m] : c0L[m];
    actB0[((size_t)d*KROW + 300 + m)*NSEQ + r] = v;
    c_final[((size_t)d*NSEQ + r)*M + m] = v;
}

__global__ void sort_kernel(const int* __restrict__ blank_sup, const int* __restrict__ blank_tgt,
                            int* __restrict__ perm, int* __restrict__ lenR, int* __restrict__ tmax)
{
    __shared__ int L0[NSEQ], L1[NSEQ];
    int tid = threadIdx.x;                       // 384 threads
    int blank = (tid < NSUP) ? blank_sup[tid] : blank_tgt[tid - NSUP];
    int l0 = blank, l1 = (T-1) - blank;
    L0[tid] = l0; L1[tid] = l1;
    __syncthreads();
    int r0 = 0, r1 = 0;
    for (int j = 0; j < NSEQ; ++j) {
        int c = L0[j]; r0 += (c > l0) || (c == l0 && j < tid);
        int d = L1[j]; r1 += (d > l1) || (d == l1 && j < tid);
    }
    perm[r0] = tid;        lenR[r0] = l0;
    perm[NSEQ + r1] = tid; lenR[NSEQ + r1] = l1;
    __syncthreads();
    if (tid < 2*NCT) {
        int dir = tid / NCT, t = tid % NCT;
        tmax[tid] = lenR[dir*NSEQ + t*CT];       // descending -> first rank in tile is max
    }
}

// -------- fused per-step kernel: 768 compute blocks + 12 gather blocks --------
// compute block = (ct, dir, mt): 16m x 3g x 32c; 4 waves = K splits of 200 ticks.
// lane = ml(16) x cg(4); lane tile = 1m x 3g x 8c (24 acc).
// A (weights) via LDS: staged b128, read b64 per 2 ticks. B (acts) global->reg, ring-4.
__global__ __launch_bounds__(256, 3)
void step_kernel(int s,
                 const float* __restrict__ actB_cur, float* __restrict__ actB_next,
                 float* __restrict__ c_final,
                 const float* __restrict__ WL, const float* __restrict__ UL, const float* __restrict__ bL,
                 const float* __restrict__ WR, const float* __restrict__ UR, const float* __restrict__ bR,
                 const int* __restrict__ perm, const int* __restrict__ lenR, const int* __restrict__ tmax,
                 const int* __restrict__ sup_tok, const int* __restrict__ tgt_tok,
                 const float* __restrict__ emb)
{
    const int bid = blockIdx.x;
    const int tid = threadIdx.x;

    if (bid >= NCOMP) {
        // ---- gather x for step s+1 into actB_next (coalesced: lane = rank) ----
        const int gb = bid - NCOMP;              // 0..11
        const int d  = gb / 6;
        const int rt = gb % 6;                   // 64-rank tile
        const int sn = s + 1;
        if (sn >= NSTEP) return;
        if (sn >= tmax[d*NCT + 2*rt]) return;    // both 32-tiles finished
        const int rr = tid & 63;
        const int kk = tid >> 6;                 // 0..3
        const int rank = rt*64 + rr;
        const int ch = perm[d*NSEQ + rank];
        const int tpos = d ? (T-1 - sn) : sn;
        const int tok = (ch < NSUP) ? sup_tok[ch*T + tpos] : tgt_tok[(ch-NSUP)*T + tpos];
        const float* src = emb + (size_t)tok*D + kk;
        float* dst = actB_next + (size_t)d*KROW*NSEQ + rank;
        #pragma unroll 5
        for (int k4 = 0; k4 < 75; ++k4)
            dst[(size_t)(k4*4 + kk)*NSEQ] = src[k4*4];
        return;
    }
    if (s < 0) return;

    // bid = ct*64 + d*32 + mt -> blocks sharing weight panel (d,mt) share bid%8 (XCD)
    const int ct = bid >> 6;
    const int dm = bid & 63;
    const int d  = dm >> 5;
    const int mt = dm & 31;
    if (s >= tmax[d*NCT + ct]) return;

    __shared__ __align__(16) float smem[SMSZ];

    const int ks   = tid >> 6;                   // wave = K split
    const int lane = tid & 63;
    const int ml   = lane >> 2;                  // 0..15: m within tile
    const int cg   = lane & 3;                   // 0..3: chain octet
    const int rank0 = ct*CT;
    const int m0 = mt*MT;

    const float* Wd = d ? WR : WL;
    const float* Ud = d ? UR : UL;
    const float* bias = d ? bR : bL;

    float* As = smem + ks*APW;                   // [48 rows g*16+ml][28]

    // ---- hoisted A staging: 240 f4 slots = 48 rows x 5 kq; slot = lane + 64*i ----
    const float* aW[4]; const float* aU[4]; float* aD[4];
    #pragma unroll
    for (int i = 0; i < 4; ++i) {
        int slot = lane + 64*i; if (slot >= 240) slot = 239;
        int row = slot/5, kq = slot%5;
        int g = row >> 4, mr = row & 15;
        int m = m0 + mr; if (m >= M) m = M-1;    // clamp (update discards)
        aW[i] = Wd + (size_t)(g*M + m)*D + kq*4;
        aU[i] = Ud + (size_t)(g*M + m)*M + kq*4;
        aD[i] = As + row*ASTR + kq*4;
    }
    const bool a3 = (lane < 48);

    float4 aR4[4];
    auto ldA = [&](int gc){
        const int off = (gc < 15) ? gc*CHK : gc*CHK - 300;
        const bool isx = (gc < 15);
        aR4[0] = *(const float4*)((isx ? aW[0] : aU[0]) + off);
        aR4[1] = *(const float4*)((isx ? aW[1] : aU[1]) + off);
        aR4[2] = *(const float4*)((isx ? aW[2] : aU[2]) + off);
        if (a3) aR4[3] = *(const float4*)((isx ? aW[3] : aU[3]) + off);
    };
    auto wrA = [&](){
        *(float4*)aD[0] = aR4[0];
        *(float4*)aD[1] = aR4[1];
        *(float4*)aD[2] = aR4[2];
        if (a3) *(float4*)aD[3] = aR4[3];
    };

    float4 acc[3][2];
    #pragma unroll
    for (int g = 0; g < 3; ++g) { acc[g][0] = make_float4(0.f,0.f,0.f,0.f);
                                  acc[g][1] = make_float4(0.f,0.f,0.f,0.f); }

    const float* Ard = As + ml*ASTR;             // rows at +0, +16*ASTR, +32*ASTR
    const float* bp  = actB_cur + ((size_t)d*KROW + ks*200)*NSEQ + rank0 + cg*8;

    // ---- B ring-4 prologue ----
    float4 bc[4][2];
    #pragma unroll
    for (int q = 0; q < 4; ++q) {
        bc[q][0] = *(const float4*)(bp + (size_t)q*NSEQ);
        bc[q][1] = *(const float4*)(bp + (size_t)q*NSEQ + 4);
    }

#define FMA8(AC, AV, B0, B1) \
    AC[0].x += (AV)*(B0).x; AC[0].y += (AV)*(B0).y; AC[0].z += (AV)*(B0).z; AC[0].w += (AV)*(B0).w; \
    AC[1].x += (AV)*(B1).x; AC[1].y += (AV)*(B1).y; AC[1].z += (AV)*(B1).z; AC[1].w += (AV)*(B1).w;

    ldA(ks*CKS);
    for (int ck = 0; ck < CKS; ++ck) {
        wrA();                                   // per-wave DS in-order: reads below see these
        if (ck + 1 < CKS) ldA(ks*CKS + ck + 1);  // prefetch next A chunk
        #pragma unroll
        for (int t2 = 0; t2 < 10; ++t2) {
            const int kk = t2*2;
            float2 a0 = *(const float2*)(Ard + kk);
            float2 a1 = *(const float2*)(Ard + 16*ASTR + kk);
            float2 a2 = *(const float2*)(Ard + 32*ASTR + kk);
            #pragma unroll
            for (int sub = 0; sub < 2; ++sub) {
                const int tt = kk + sub;         // 0..19 static
                const int rg = tt & 3;           // static ring index
                float ax0 = sub ? a0.y : a0.x;
                float ax1 = sub ? a1.y : a1.x;
                float ax2 = sub ? a2.y : a2.x;
                float4 b0 = bc[rg][0], b1 = bc[rg][1];
                int gt = ck*CHK + tt;
                if (gt + 4 < 200) {              // refill ring slot for tick gt+4
                    bc[rg][0] = *(const float4*)(bp + (size_t)(gt+4)*NSEQ);
                    bc[rg][1] = *(const float4*)(bp + (size_t)(gt+4)*NSEQ + 4);
                }
                FMA8(acc[0], ax0, b0, b1);
                FMA8(acc[1], ax1, b0, b1);
                FMA8(acc[2], ax2, b0, b1);
            }
        }
    }
#undef FMA8

    // ---- cross-split reduction through LDS (reuse smem: [ks][ml 16][3][32] = 6144) ----
    __syncthreads();
    float* red = smem;
    #pragma unroll
    for (int g = 0; g < 3; ++g) {
        *(float4*)&red[((ks*MT + ml)*3 + g)*CT + cg*8]     = acc[g][0];
        *(float4*)&red[((ks*MT + ml)*3 + g)*CT + cg*8 + 4] = acc[g][1];
    }
    __syncthreads();

    // ---- final: sum splits + bias, gates, cell update (2 cells per thread) ----
    #pragma unroll
    for (int q = 0; q < 2; ++q) {
        int cell = tid*2 + q;                    // 512 = 16 ml x 32 c
        int mr = cell >> 5, c = cell & 31;
        int m = m0 + mr;
        if (m < M) {
            float g0 = bias[m], g1 = bias[M + m], g2 = bias[2*M + m];
            #pragma unroll
            for (int kq = 0; kq < KSPL; ++kq) {
                g0 += red[((kq*MT + mr)*3 + 0)*CT + c];
                g1 += red[((kq*MT + mr)*3 + 1)*CT + c];
                g2 += red[((kq*MT + mr)*3 + 2)*CT + c];
            }
            int rank = rank0 + c;
            int len  = lenR[d*NSEQ + rank];
            size_t cidx = ((size_t)d*KROW + 300 + m)*NSEQ + rank;
            float cold = actB_cur[cidx];
            float f  = sigmoidf_(g0);
            float i2 = sigmoidf_(g1);
            float cb = tanhf(g2);
            float cn = (s < len) ? (f*cold + i2*cb) : cold;
            actB_next[cidx] = cn;
            if (s == len - 1) {
                int ch = perm[d*NSEQ + rank];
                c_final[((size_t)d*NSEQ + ch)*M + m] = cn;
            }
        }
    }
}

__global__ void env_kernel(const float* __restrict__ l_states, const float* __restrict__ r_states,
                           const float* __restrict__ Wo, const float* __restrict__ Uo,
                           const float* __restrict__ bo,
                           float* __restrict__ env)
{
    __shared__ __align__(16) float l[M];
    __shared__ __align__(16) float r[M];
    const int i = blockIdx.x;
    const int tid = threadIdx.x;
    for (int m=tid; m<M; m+=blockDim.x){ l[m]=l_states[i*M+m]; r[m]=r_states[i*M+m]; }
    __syncthreads();
    for (int d=tid; d<D; d+=blockDim.x) {
        const float4* wo = reinterpret_cast<const float4*>(Wo + (size_t)d*M);
        const float4* uo = reinterpret_cast<const float4*>(Uo + (size_t)d*M);
        const float4* lv = reinterpret_cast<const float4*>(l);
        const float4* rv = reinterpret_cast<const float4*>(r);
        float acc = bo[d];
        #pragma unroll 5
        for (int q=0; q<M/4; ++q) {
            float4 a=wo[q], bv=lv[q], u=uo[q], rr=rv[q];
            acc += a.x*bv.x + a.y*bv.y + a.z*bv.z + a.w*bv.w;
            acc += u.x*rr.x + u.y*rr.y + u.z*rr.z + u.w*rr.w;
        }
        env[i*D + d] = tanhf(acc);
    }
}

__global__ void episode_kernel(const float* __restrict__ env, const int* __restrict__ target_y,
                               float* __restrict__ flags, float* __restrict__ losses)
{
    const int b = blockIdx.x;
    const int lane = threadIdx.x;
    const float* tgt = env + (size_t)(NSUP + b)*D;

    float tn = 0.f;
    for (int d=lane; d<D; d+=64){ float v=tgt[d]; tn += v*v; }
    for (int off=32; off; off>>=1) tn += __shfl_down(tn, off);
    tn = __shfl(tn, 0);

    float z[NW];
    for (int n=0; n<NW; ++n){
        const float* sup = env + (size_t)(b*NW + n)*D;
        float dot=0.f, sn=0.f;
        for (int d=lane; d<D; d+=64){ float sv=sup[d], tv=tgt[d]; dot+=sv*tv; sn+=sv*sv; }
        for (int off=32; off; off>>=1){ dot += __shfl_down(dot,off); sn += __shfl_down(sn,off); }
        dot = __shfl(dot,0); sn = __shfl(sn,0);
        float denom = fmaxf(sqrtf(sn)*sqrtf(tn), 1e-8f);
        z[n] = dot/denom*10.0f;
    }

    if (lane==0){
        float mx=z[0];
        for(int n=1;n<NW;n++) mx=fmaxf(mx,z[n]);
        float se=0.f; float p[NW];
        for(int n=0;n<NW;n++){ p[n]=expf(z[n]-mx); se+=p[n]; }
        for(int n=0;n<NW;n++) p[n]/=se;
        int am=0; float bv=p[0];
        for(int n=1;n<NW;n++) if(p[n]>bv){bv=p[n];am=n;}
        int y = target_y[b];
        flags[b] = (am==y)?1.0f:0.0f;
        float mx2=p[0]; for(int n=1;n<NW;n++) mx2=fmaxf(mx2,p[n]);
        float se2=0.f; for(int n=0;n<NW;n++) se2+=expf(p[n]-mx2);
        losses[b] = -(p[y]-mx2-logf(se2));
    }
}

__global__ void finalize_kernel(const float* __restrict__ flags, const float* __restrict__ losses,
                                float* __restrict__ out)
{
    const int lane = threadIdx.x; // 64 threads
    float f = flags[lane], l = losses[lane];
    for (int off=32; off; off>>=1){ f += __shfl_down(f,off); l += __shfl_down(l,off); }
    if (lane==0){ out[0] = f/(float)B; out[1] = l/(float)B; }
}

extern "C" void kernel_launch(void* const* d_in, const int* in_sizes, int n_in,
                              void* d_out, int out_size, void* d_ws, size_t ws_size,
                              hipStream_t stream) {
    const int*   sup_tok   = (const int*)d_in[0];
    const int*   tgt_tok   = (const int*)d_in[1];
    const int*   blank_sup = (const int*)d_in[2];
    const int*   blank_tgt = (const int*)d_in[3];
    const int*   target_y  = (const int*)d_in[4];
    const float* emb = (const float*)d_in[5];
    const float* WL  = (const float*)d_in[6];
    const float* UL  = (const float*)d_in[7];
    const float* bL  = (const float*)d_in[8];
    const float* WR  = (const float*)d_in[9];
    const float* UR  = (const float*)d_in[10];
    const float* bR  = (const float*)d_in[11];
    const float* Wo  = (const float*)d_in[12];
    const float* Uo  = (const float*)d_in[13];
    const float* bo  = (const float*)d_in[14];
    const float* c0L = (const float*)d_in[15];
    const float* c0R = (const float*)d_in[16];

    const size_t ACTSZ = (size_t)2*KROW*NSEQ;           // 614400 floats
    float* ws_f = (float*)d_ws;
    float* actB0   = ws_f;
    float* actB1   = actB0 + ACTSZ;
    float* c_final = actB1 + ACTSZ;                     // [2*384*500]
    float* env     = c_final + 2*NSEQ*M;                // [384*300]
    float* flags   = env + NSEQ*D;                      // [64]
    float* losses  = flags + B;                         // [64]
    int*   perm    = (int*)(losses + B);                // [2*384]
    int*   lenR    = perm + 2*NSEQ;                     // [2*384]
    int*   tmax    = lenR + 2*NSEQ;                     // [24]

    init_kernel<<<(2*M*NSEQ + 255)/256, 256, 0, stream>>>(c0L, c0R, actB0, c_final);
    sort_kernel<<<1, NSEQ, 0, stream>>>(blank_sup, blank_tgt, perm, lenR, tmax);

    // prologue: gather x for step 0 into actB0 (compute blocks no-op at s=-1)
    step_kernel<<<NCOMP + NGATH, 256, 0, stream>>>(-1, actB1, actB0, c_final,
                                                   WL, UL, bL, WR, UR, bR,
                                                   perm, lenR, tmax, sup_tok, tgt_tok, emb);
    for (int s = 0; s < NSTEP; ++s) {
        float* cur  = (s & 1) ? actB1 : actB0;
        float* next = (s & 1) ? actB0 : actB1;
        step_kernel<<<NCOMP + NGATH, 256, 0, stream>>>(s, cur, next, c_final,
                                                       WL, UL, bL, WR, UR, bR,
                                                       perm, lenR, tmax, sup_tok, tgt_tok, emb);
    }

    env_kernel<<<NSEQ, 256, 0, stream>>>(c_final, c_final + NSEQ*M, Wo, Uo, bo, env);
    episode_kernel<<<B, 64, 0, stream>>>(env, target_y, flags, losses);
    finalize_kernel<<<1, 64, 0, stream>>>(flags, losses, (float*)d_out);
}